// Round 1
// 360.997 us; speedup vs baseline: 1.0106x; 1.0106x over previous
//
#include <hip/hip_runtime.h>

typedef unsigned short u16;
typedef __attribute__((ext_vector_type(8))) short short8;
typedef __attribute__((ext_vector_type(4))) unsigned short ushort4v;
typedef __attribute__((ext_vector_type(4))) float float4v;

#define TVB 7500
#define CTVB 480000

static __device__ __forceinline__ float bf2f(u16 a) {
    union { unsigned u; float f; } x; x.u = ((unsigned)a) << 16; return x.f;
}
static __device__ __forceinline__ u16 f2bf(float f) {
    union { float f; unsigned u; } x; x.f = f;
    unsigned r = x.u + 0x7fffu + ((x.u >> 16) & 1u);
    return (u16)(r >> 16);
}

// ---------------- Kernel A: attention score partials S_i[n,u,v] ----------------
// grid (15, 64), block 256. Each block: 20 t's (5 groups of 4).
// S_i[u,v] = sum_{ci,t} (Wa_i x + ba)[ci,t,u] * (Wb_i x + bb)[ci,t,v]
__global__ __launch_bounds__(256, 3) void kA(
    const float* __restrict__ xg, const float* __restrict__ Wa, const float* __restrict__ ba,
    const float* __restrict__ Wb, const float* __restrict__ bb, float* __restrict__ Sws)
{
    __shared__ u16 xT[4][32][72];   // xT[tt][u][c] : X_t transposed (B-operand for W@X)
    __shared__ u16 asT[3][32][72];  // a^T : [i][u][k=tt*16+ci]
    __shared__ u16 bsT[3][32][72];  // b^T : [i][v][k]
    const int tid  = threadIdx.x;
    const int lane = tid & 63;
    const int w    = tid >> 6;
    const int l15  = lane & 15;
    const int q    = lane >> 4;
    const int n    = blockIdx.y;
    const int t0   = blockIdx.x * 20;

    // zero the pad rows u=25..31 of xT once (never touched by staging)
    for (int e = tid; e < 4 * 7 * 72; e += 256) {
        int tt = e / (7 * 72);
        int r  = e - tt * (7 * 72);
        xT[tt][25 + r / 72][r % 72] = 0;
    }

    // Unit mapping: 12 units (tt,i) = unit (tt*3+i); wave w owns units {w, w+4, w+8}.
    // All 4 waves now participate in stage 1 (was: wave 3 idle).
    int tts[3], iis[3];
    #pragma unroll
    for (int m = 0; m < 3; ++m) { int u = w + 4 * m; tts[m] = u / 3; iis[m] = u - 3 * tts[m]; }

    // Preload Wa/Wb A-frags for this wave's 3 units. Static register indexing
    // (index by m, not by runtime i) so nothing goes to scratch. A[m=ci][k=c].
    short8 waf[3][2], wbf[3][2];
    float ba_r[3][4], bb_r[3][4];
    #pragma unroll
    for (int m = 0; m < 3; ++m) {
        const int i = iis[m];
        const float* wap = Wa + i * 1024;
        const float* wbp = Wb + i * 1024;
        #pragma unroll
        for (int kf = 0; kf < 2; ++kf) {
            short8 fa, fb;
            int base = l15 * 64 + kf * 32 + q * 8;
            #pragma unroll
            for (int j = 0; j < 8; ++j) {
                fa[j] = (short)f2bf(wap[base + j]);
                fb[j] = (short)f2bf(wbp[base + j]);
            }
            waf[m][kf] = fa; wbf[m][kf] = fb;
        }
        #pragma unroll
        for (int r = 0; r < 4; ++r) {
            ba_r[m][r] = ba[i * 16 + q * 4 + r];
            bb_r[m][r] = bb[i * 16 + q * 4 + r];
        }
    }

    float4v accS[3];
    #pragma unroll
    for (int i = 0; i < 3; ++i) accS[i] = (float4v){0.f, 0.f, 0.f, 0.f};

    const float* xb = xg + (size_t)n * CTVB;

    for (int g = 0; g < 5; ++g) {
        __syncthreads();
        // stage 4 t's, transposed, via float4 loads: 100 floats per c-run = 25 float4
        // (t0+g*4)*25 and c*TVB are multiples of 4 floats -> 16B aligned.
        for (int e = tid; e < 1600; e += 256) {
            int c = e / 25;
            int j = e - c * 25;
            float4v xv = *(const float4v*)(xb + (size_t)c * TVB + (t0 + g * 4) * 25 + j * 4);
            #pragma unroll
            for (int k2 = 0; k2 < 4; ++k2) {
                int idx = j * 4 + k2;      // 0..99 = tt*25 + u
                int tt = idx / 25;
                int uu = idx - tt * 25;
                xT[tt][uu][c] = f2bf(xv[k2]);
            }
        }
        __syncthreads();
        // Stage 1: each wave computes its 3 (tt,i) units: a,b = (W x + bias)
        #pragma unroll
        for (int m = 0; m < 3; ++m) {
            const int tt = tts[m];
            const int i  = iis[m];
            float4v aA0 = {0,0,0,0}, aA1 = {0,0,0,0}, aB0 = {0,0,0,0}, aB1 = {0,0,0,0};
            #pragma unroll
            for (int kf = 0; kf < 2; ++kf) {
                short8 x0 = *(const short8*)&xT[tt][l15][kf * 32 + q * 8];
                short8 x1 = *(const short8*)&xT[tt][16 + l15][kf * 32 + q * 8];
                aA0 = __builtin_amdgcn_mfma_f32_16x16x32_bf16(waf[m][kf], x0, aA0, 0, 0, 0);
                aA1 = __builtin_amdgcn_mfma_f32_16x16x32_bf16(waf[m][kf], x1, aA1, 0, 0, 0);
                aB0 = __builtin_amdgcn_mfma_f32_16x16x32_bf16(wbf[m][kf], x0, aB0, 0, 0, 0);
                aB1 = __builtin_amdgcn_mfma_f32_16x16x32_bf16(wbf[m][kf], x1, aB1, 0, 0, 0);
            }
            ushort4v pa0, pa1, pb0, pb1;
            #pragma unroll
            for (int r = 0; r < 4; ++r) {
                pa0[r] = f2bf(aA0[r] + ba_r[m][r]);
                pa1[r] = f2bf(aA1[r] + ba_r[m][r]);
                pb0[r] = f2bf(aB0[r] + bb_r[m][r]);
                pb1[r] = f2bf(aB1[r] + bb_r[m][r]);
            }
            int kb = tt * 16 + q * 4;   // k slot = tt*16 + ci, ci = q*4+r
            *(ushort4v*)&asT[i][l15][kb]      = pa0;
            *(ushort4v*)&asT[i][16 + l15][kb] = pa1;
            *(ushort4v*)&bsT[i][l15][kb]      = pb0;
            *(ushort4v*)&bsT[i][16 + l15][kb] = pb1;
        }
        __syncthreads();
        // Stage 2: S_i += a^T b over this group's K=64. Wave -> (mt,nt) combo.
        const int mt = w >> 1, nt = w & 1;
        #pragma unroll
        for (int i = 0; i < 3; ++i) {
            #pragma unroll
            for (int ks = 0; ks < 2; ++ks) {
                short8 af  = *(const short8*)&asT[i][mt * 16 + l15][ks * 32 + q * 8];
                short8 bf_ = *(const short8*)&bsT[i][nt * 16 + l15][ks * 32 + q * 8];
                accS[i] = __builtin_amdgcn_mfma_f32_16x16x32_bf16(af, bf_, accS[i], 0, 0, 0);
            }
        }
    }
    const int mt = w >> 1, nt = w & 1;
    #pragma unroll
    for (int i = 0; i < 3; ++i) {
        #pragma unroll
        for (int r = 0; r < 4; ++r) {
            int u = mt * 16 + q * 4 + r;
            int v = nt * 16 + l15;
            if (u < 25 && v < 25)
                atomicAdd(&Sws[(i * 64 + n) * 625 + u * 25 + v], accS[i][r]);
        }
    }
}

// ---------------- Kernel S: softmax over u (dim -2), + A_static + graph_attn ----------------
__global__ __launch_bounds__(64) void kS(float* __restrict__ Sws,
    const float* __restrict__ Ast, const float* __restrict__ Gat)
{
    int g = blockIdx.x;       // g = i*64 + n
    int i = g >> 6;
    int v = threadIdx.x;
    if (v >= 25) return;
    float vals[25];
    float m = -1e30f;
    #pragma unroll
    for (int u = 0; u < 25; ++u) {
        float s = Sws[g * 625 + u * 25 + v] * (1.0f / 4800.0f);
        vals[u] = s;
        m = fmaxf(m, s);
    }
    float sum = 0.f;
    #pragma unroll
    for (int u = 0; u < 25; ++u) { float e = __expf(vals[u] - m); vals[u] = e; sum += e; }
    float isum = 1.f / sum;
    #pragma unroll
    for (int u = 0; u < 25; ++u) {
        int idx = i * 625 + u * 25 + v;
        Sws[g * 625 + u * 25 + v] = vals[u] * isum + Ast[idx] + Gat[idx];
    }
}

// ---------------- Kernel B: out = relu(BN(sum_i Wg_i @ (X_t @ P_i)) + x) ----------------
// grid (75, 64), block 256. 4 t's per block. LDS = 39424 B -> 4 blocks/CU.
__global__ __launch_bounds__(256, 4) void kB(
    const float* __restrict__ xg, const float* __restrict__ Wgp, const float* __restrict__ bgp,
    const float* __restrict__ gam, const float* __restrict__ bet, const float* __restrict__ rmu,
    const float* __restrict__ rva, const float* __restrict__ attnw, float* __restrict__ outg)
{
    __shared__ u16 xsu[4][64][40];   // x[c][u], stride 40 (80B = 20 banks) kills epilogue 4-way conflict
    __shared__ u16 ysT[32][200];     // Ycat^T : [v][k=i*64+c]
    __shared__ u16 pTs[3][32][32];   // attn^T : [i][v][u], zero-padded
    const int tid  = threadIdx.x;
    const int lane = tid & 63;
    const int w    = tid >> 6;
    const int l15  = lane & 15;
    const int q    = lane >> 4;
    const int n    = blockIdx.y;
    const int t0   = blockIdx.x * 4;

    for (int e = tid; e < 3 * 32 * 32; e += 256) ((u16*)pTs)[e] = 0;
    const float* xb = xg + (size_t)n * CTVB;
    // x staging via float4: 4 consecutive t per c = 100 floats = 25 float4 (16B aligned)
    for (int e = tid; e < 1600; e += 256) {
        int c = e / 25;
        int j = e - c * 25;
        float4v xv = *(const float4v*)(xb + (size_t)c * TVB + t0 * 25 + j * 4);
        #pragma unroll
        for (int k = 0; k < 4; ++k) {
            int idx = j * 4 + k;        // 0..99 = tt*25 + u
            int tt = idx / 25;
            int u  = idx - tt * 25;
            xsu[tt][c][u] = f2bf(xv[k]);
        }
    }
    // zero pads u=25..31 (cols 32..39 never read)
    for (int e = tid; e < 4 * 64 * 7; e += 256) {
        int tt = e / (64 * 7);
        int r  = e - tt * (64 * 7);
        xsu[tt][r / 7][25 + r % 7] = 0;
    }
    __syncthreads();
    for (int e = tid; e < 1875; e += 256) {
        int i = e / 625;
        int r = e - i * 625;
        int u = r / 25;
        int v = r - u * 25;
        pTs[i][v][u] = f2bf(attnw[(i * 64 + n) * 625 + r]);
    }
    // Wg A-frags in registers for the whole kernel. A[m=o][k=i*64+c], k-frag kf: k=kf*32+q*8+j
    short8 wgf[6];
    const int o_row = w * 16 + l15;
    #pragma unroll
    for (int kf = 0; kf < 6; ++kf) {
        int i  = kf >> 1;
        int c0 = (kf & 1) * 32 + q * 8;
        const float* p = Wgp + i * 4096 + o_row * 64 + c0;
        short8 f;
        #pragma unroll
        for (int j = 0; j < 8; ++j) f[j] = (short)f2bf(p[j]);
        wgf[kf] = f;
    }
    // BN constants per lane (o = w*16 + q*4 + r)
    float invr[4], add0r[4];
    #pragma unroll
    for (int r = 0; r < 4; ++r) {
        int o = w * 16 + q * 4 + r;
        float gv = gam[o], bt = bet[o], mu = rmu[o], vv = rva[o];
        float bgs = bgp[o] + bgp[64 + o] + bgp[128 + o];
        float iv = gv * rsqrtf(vv + 1e-5f);
        invr[r] = iv;
        add0r[r] = (bgs - mu) * iv + bt;
    }
    __syncthreads();
    // P B-frags in registers: B[k=u][n=v]
    short8 pf[3][2];
    #pragma unroll
    for (int i = 0; i < 3; ++i)
        #pragma unroll
        for (int nt = 0; nt < 2; ++nt)
            pf[i][nt] = *(const short8*)&pTs[i][nt * 16 + l15][q * 8];

    for (int tl = 0; tl < 4; ++tl) {
        // Phase A: Y_i = X_t @ P_i  (A = x strip per wave, K=u padded 32)
        short8 xf = *(const short8*)&xsu[tl][w * 16 + l15][q * 8];
        #pragma unroll
        for (int i = 0; i < 3; ++i) {
            #pragma unroll
            for (int nt = 0; nt < 2; ++nt) {
                float4v acc = {0, 0, 0, 0};
                acc = __builtin_amdgcn_mfma_f32_16x16x32_bf16(xf, pf[i][nt], acc, 0, 0, 0);
                ushort4v pk;
                #pragma unroll
                for (int r = 0; r < 4; ++r) pk[r] = f2bf(acc[r]);
                *(ushort4v*)&ysT[nt * 16 + l15][i * 64 + w * 16 + q * 4] = pk;
            }
        }
        __syncthreads();
        // Phase B: Out_t = WgCat(64x192) @ Ycat(192x25pad32)
        #pragma unroll
        for (int nt = 0; nt < 2; ++nt) {
            float4v acc = {0, 0, 0, 0};
            #pragma unroll
            for (int kf = 0; kf < 6; ++kf) {
                short8 yf = *(const short8*)&ysT[nt * 16 + l15][kf * 32 + q * 8];
                acc = __builtin_amdgcn_mfma_f32_16x16x32_bf16(wgf[kf], yf, acc, 0, 0, 0);
            }
            int v = nt * 16 + l15;
            if (v < 25) {
                size_t ob = (size_t)n * CTVB + (size_t)(t0 + tl) * 25 + v;
                #pragma unroll
                for (int r = 0; r < 4; ++r) {
                    int o = w * 16 + q * 4 + r;
                    float xres = bf2f(xsu[tl][o][v]);
                    float val = fmaf(acc[r], invr[r], add0r[r]) + xres;
                    val = fmaxf(val, 0.f);
                    outg[ob + (size_t)o * TVB] = val;
                }
            }
        }
        __syncthreads();
    }
}

extern "C" void kernel_launch(void* const* d_in, const int* in_sizes, int n_in,
                              void* d_out, int out_size, void* d_ws, size_t ws_size,
                              hipStream_t stream) {
    const float* x    = (const float*)d_in[0];
    const float* Ast  = (const float*)d_in[1];
    const float* Gat  = (const float*)d_in[2];
    const float* Wg   = (const float*)d_in[3];
    const float* bg   = (const float*)d_in[4];
    const float* Wa   = (const float*)d_in[5];
    const float* ba   = (const float*)d_in[6];
    const float* Wb   = (const float*)d_in[7];
    const float* bb   = (const float*)d_in[8];
    const float* gam  = (const float*)d_in[9];
    const float* bet  = (const float*)d_in[10];
    const float* rmu  = (const float*)d_in[11];
    const float* rva  = (const float*)d_in[12];
    float* out = (float*)d_out;
    float* Sws = (float*)d_ws;   // 192*625 floats = 480 KB

    hipMemsetAsync(Sws, 0, 192 * 625 * sizeof(float), stream);
    kA<<<dim3(15, 64), 256, 0, stream>>>(x, Wa, ba, Wb, bb, Sws);
    kS<<<dim3(192), 64, 0, stream>>>(Sws, Ast, Gat);
    kB<<<dim3(75, 64), 256, 0, stream>>>(x, Wg, bg, gam, bet, rmu, rva, Sws, out);
}